// Round 1
// baseline (117.678 us; speedup 1.0000x reference)
//
#include <hip/hip_runtime.h>

#define NBDT_BATCH 16384
#define NBDT_C 1024

// sigmoid(x) = 1/(1+exp(-x)); v_exp + v_rcp, ~1 ulp each — far inside the
// 3.39e-4 absolute threshold on values <= 1.
__device__ __forceinline__ float fast_sigmoid(float x) {
    return __builtin_amdgcn_rcpf(1.0f + __expf(-x));
}

// One wave (64 lanes) per row; lane L owns the 16 contiguous classes
// [16L, 16L+16). Entire tree lives in registers + 6 shfl_xor stages.
__global__ __launch_bounds__(256) void nbdt_kernel(const float* __restrict__ x,
                                                   float* __restrict__ y) {
    const int gtid = blockIdx.x * 256 + threadIdx.x;
    const int row  = gtid >> 6;           // one row per wave
    const int lane = threadIdx.x & 63;
    const size_t base = (size_t)row * NBDT_C + (size_t)lane * 16;

    const float4* xin = reinterpret_cast<const float4*>(x + base);
    float4 v0 = xin[0];
    float4 v1 = xin[1];
    float4 v2 = xin[2];
    float4 v3 = xin[3];
    float e[16] = {v0.x, v0.y, v0.z, v0.w,
                   v1.x, v1.y, v1.z, v1.w,
                   v2.x, v2.y, v2.z, v2.w,
                   v3.x, v3.y, v3.z, v3.w};

    // ---- up-sweep: dyadic block sums ----
    float s2[8], s4[4], s8[2], s16;
#pragma unroll
    for (int i = 0; i < 8; ++i) s2[i] = e[2 * i] + e[2 * i + 1];
#pragma unroll
    for (int i = 0; i < 4; ++i) s4[i] = s2[2 * i] + s2[2 * i + 1];
#pragma unroll
    for (int i = 0; i < 2; ++i) s8[i] = s4[2 * i] + s4[2 * i + 1];
    s16 = s8[0] + s8[1];

    // cross-lane butterflies: after each stage the lane holds the sum of its
    // enclosing 2^k-lane block; the shuffled value is the sibling block's sum.
    float t16 = __shfl_xor(s16, 1);
    float s32 = s16 + t16;
    float t32 = __shfl_xor(s32, 2);
    float s64 = s32 + t32;
    float t64 = __shfl_xor(s64, 4);
    float s128 = s64 + t64;
    float t128 = __shfl_xor(s128, 8);
    float s256 = s128 + t128;
    float t256 = __shfl_xor(s256, 16);
    float s512 = s256 + t256;
    float t512 = __shfl_xor(s512, 32);

    // ---- path prefix: tree levels with child-block >= 16 are uniform over
    // this lane's 16 leaves. p_own = sigmoid((S_own - S_sib)/blk). ----
    float P = fast_sigmoid((s512 - t512) * (1.0f / 512.0f));
    P *= fast_sigmoid((s256 - t256) * (1.0f / 256.0f));
    P *= fast_sigmoid((s128 - t128) * (1.0f / 128.0f));
    P *= fast_sigmoid((s64 - t64) * (1.0f / 64.0f));
    P *= fast_sigmoid((s32 - t32) * (1.0f / 32.0f));
    P *= fast_sigmoid((s16 - t16) * (1.0f / 16.0f));

    // ---- within-lane down-sweep (blk = 8, 4, 2, 1). Sibling prob is the
    // exact complement: c_sib = c_parent - c_own. ----
    float c8[2];
    {
        float p = fast_sigmoid((s8[0] - s8[1]) * 0.125f);
        c8[0] = P * p;
        c8[1] = P - c8[0];
    }
    float c4[4];
#pragma unroll
    for (int h = 0; h < 2; ++h) {
        float p = fast_sigmoid((s4[2 * h] - s4[2 * h + 1]) * 0.25f);
        c4[2 * h] = c8[h] * p;
        c4[2 * h + 1] = c8[h] - c4[2 * h];
    }
    float c2[8];
#pragma unroll
    for (int q = 0; q < 4; ++q) {
        float p = fast_sigmoid((s2[2 * q] - s2[2 * q + 1]) * 0.5f);
        c2[2 * q] = c4[q] * p;
        c2[2 * q + 1] = c4[q] - c2[2 * q];
    }
    float o[16];
#pragma unroll
    for (int k = 0; k < 8; ++k) {
        float p = fast_sigmoid(e[2 * k] - e[2 * k + 1]);
        o[2 * k] = c2[k] * p;
        o[2 * k + 1] = c2[k] - o[2 * k];
    }

    float4* yout = reinterpret_cast<float4*>(y + base);
    yout[0] = make_float4(o[0], o[1], o[2], o[3]);
    yout[1] = make_float4(o[4], o[5], o[6], o[7]);
    yout[2] = make_float4(o[8], o[9], o[10], o[11]);
    yout[3] = make_float4(o[12], o[13], o[14], o[15]);
}

extern "C" void kernel_launch(void* const* d_in, const int* in_sizes, int n_in,
                              void* d_out, int out_size, void* d_ws, size_t ws_size,
                              hipStream_t stream) {
    const float* x = (const float*)d_in[0];
    float* y = (float*)d_out;
    // 16384 rows, 1 row per wave, 4 waves per 256-thread block -> 4096 blocks.
    dim3 grid(NBDT_BATCH / 4);
    dim3 block(256);
    nbdt_kernel<<<grid, block, 0, stream>>>(x, y);
}

// Round 2
// 108.725 us; speedup vs baseline: 1.0824x; 1.0824x over previous
//
#include <hip/hip_runtime.h>

#define NBDT_BATCH 16384
#define NBDT_C 1024

// sigmoid(x) = 1/(1+exp(-x)); v_exp + v_rcp, ~1 ulp each.
__device__ __forceinline__ float fast_sigmoid(float x) {
    return __builtin_amdgcn_rcpf(1.0f + __expf(-x));
}

// One wave per row. Lane i owns leaves { k*256 + 4i + j : k=0..3, j=0..3 } so
// every global load/store is lane-contiguous (lane i at byte offset 16*i
// within a 1KB chunk) -> perfectly coalesced dwordx4.
//
// Tree decomposition:
//   blk 1,2   : within the lane's 4-leaf group (e, s2)
//   blk 4..128: butterfly shfl_xor stages per k-group (sibling diffs d4..d128)
//   blk 256   : s256[k] vs s256[k^1], lane-uniform
//   blk 512   : (s256[0]+s256[1]) vs (s256[2]+s256[3]), lane-uniform
__global__ __launch_bounds__(256) void nbdt_kernel(const float* __restrict__ x,
                                                   float* __restrict__ y) {
    const int wave = (blockIdx.x * 256 + threadIdx.x) >> 6;
    const int lane = threadIdx.x & 63;
    const size_t rowbase = (size_t)wave * NBDT_C + (size_t)lane * 4;

    float e[4][4];
#pragma unroll
    for (int k = 0; k < 4; ++k) {
        float4 v = *reinterpret_cast<const float4*>(x + rowbase + k * 256);
        e[k][0] = v.x; e[k][1] = v.y; e[k][2] = v.z; e[k][3] = v.w;
    }

    float s2[4][2], s4[4], s256[4];
    float d4[4], d8[4], d16[4], d32[4], d64[4], d128[4];
#pragma unroll
    for (int k = 0; k < 4; ++k) {
        s2[k][0] = e[k][0] + e[k][1];
        s2[k][1] = e[k][2] + e[k][3];
        s4[k] = s2[k][0] + s2[k][1];
        float acc = s4[k];
        float t;
        t = __shfl_xor(acc, 1);  d4[k]   = acc - t;  acc += t;   // acc = s8
        t = __shfl_xor(acc, 2);  d8[k]   = acc - t;  acc += t;   // s16
        t = __shfl_xor(acc, 4);  d16[k]  = acc - t;  acc += t;   // s32
        t = __shfl_xor(acc, 8);  d32[k]  = acc - t;  acc += t;   // s64
        t = __shfl_xor(acc, 16); d64[k]  = acc - t;  acc += t;   // s128
        t = __shfl_xor(acc, 32); d128[k] = acc - t;  acc += t;   // s256
        s256[k] = acc;
    }

    // top two levels (lane-uniform)
    const float S512a = s256[0] + s256[1];
    const float S512b = s256[2] + s256[3];
    const float pTop = fast_sigmoid((S512a - S512b) * (1.0f / 512.0f));
    const float qTop = 1.0f - pTop;
    const float p01  = fast_sigmoid((s256[0] - s256[1]) * (1.0f / 256.0f));
    const float p23  = fast_sigmoid((s256[2] - s256[3]) * (1.0f / 256.0f));
    float P[4];
    P[0] = pTop * p01;  P[1] = pTop - P[0];
    P[2] = qTop * p23;  P[3] = qTop - P[2];

#pragma unroll
    for (int k = 0; k < 4; ++k) {
        float Pk = P[k];
        Pk *= fast_sigmoid(d128[k] * (1.0f / 128.0f));
        Pk *= fast_sigmoid(d64[k]  * (1.0f / 64.0f));
        Pk *= fast_sigmoid(d32[k]  * (1.0f / 32.0f));
        Pk *= fast_sigmoid(d16[k]  * (1.0f / 16.0f));
        Pk *= fast_sigmoid(d8[k]   * (1.0f / 8.0f));
        Pk *= fast_sigmoid(d4[k]   * (1.0f / 4.0f));

        // down-sweep: blk=2 then blk=1, complements are exact
        float c0 = Pk * fast_sigmoid((s2[k][0] - s2[k][1]) * 0.5f);
        float c1 = Pk - c0;
        float4 o;
        o.x = c0 * fast_sigmoid(e[k][0] - e[k][1]);
        o.y = c0 - o.x;
        o.z = c1 * fast_sigmoid(e[k][2] - e[k][3]);
        o.w = c1 - o.z;
        *reinterpret_cast<float4*>(y + rowbase + k * 256) = o;
    }
}

extern "C" void kernel_launch(void* const* d_in, const int* in_sizes, int n_in,
                              void* d_out, int out_size, void* d_ws, size_t ws_size,
                              hipStream_t stream) {
    const float* x = (const float*)d_in[0];
    float* y = (float*)d_out;
    // 16384 rows, 1 row per wave, 4 waves per 256-thread block -> 4096 blocks.
    dim3 grid(NBDT_BATCH / 4);
    dim3 block(256);
    nbdt_kernel<<<grid, block, 0, stream>>>(x, y);
}